// Round 12
// baseline (225.964 us; speedup 1.0000x reference)
//
#include <hip/hip_runtime.h>

#define N_NODES 50000
#define N_EDGES 1600000
#define FEATS 128
#define N_GRAPHS 512
#define N_CLASSES 16

#define NC 400      // edge chunks
#define CE 4000     // edges per chunk (NC*CE == N_EDGES)
#define NB 391      // buckets of 128 node-ids (391*128 = 50048)
#define SLAB 4608   // arena capacity per bucket (mean 4092, +8 sigma)
#define CSLAB 5632  // csr u16 slots per bucket (sum of 8-padded lo+hi segments, +8 sigma)
#define ZROW 50000  // sentinel node id -> zero row
#define SRC_MID 25000

typedef __attribute__((ext_vector_type(8))) short bf16x8;
typedef __attribute__((ext_vector_type(4))) float f32x4;

__device__ inline unsigned bf16_rne_bits(float x) {
    unsigned u = __float_as_uint(x);
    return (u + 0x7FFFu + ((u >> 16) & 1u)) >> 16;
}
__device__ inline unsigned pack_bf16(float a, float b) {
    return (bf16_rne_bits(b) << 16) | bf16_rne_bits(a);
}
__device__ inline float bf16lo(unsigned u) { return __uint_as_float(u << 16); }
__device__ inline float bf16hi(unsigned u) { return __uint_as_float(u & 0xFFFF0000u); }

// ---- A1: per-chunk bucket histograms + packed per-edge ranks; tail blocks do wsplit ----
__global__ __launch_bounds__(256) void countrank_kernel(
        const int* __restrict__ src, const int* __restrict__ dst,
        unsigned* __restrict__ ranks, unsigned* __restrict__ cntD, unsigned* __restrict__ cntS,
        const float* __restrict__ W1, const float* __restrict__ W2,
        unsigned short* __restrict__ t1h, unsigned short* __restrict__ t1l,
        unsigned short* __restrict__ t2h, unsigned short* __restrict__ t2l) {
    __shared__ unsigned hD[NB], hS[NB];
    if (blockIdx.x >= NC) {   // W -> transposed split-bf16 pair (128 blocks)
        int b = blockIdx.x - NC;
        const float* W = (b < 64) ? W1 : W2;
        unsigned short* th = (b < 64) ? t1h : t2h;
        unsigned short* tl = (b < 64) ? t1l : t2l;
        int idx = (b & 63) * 256 + threadIdx.x;
        int k = idx >> 7;
        int col = idx & 127;
        float w = W[idx];
        unsigned hb = bf16_rne_bits(w);
        float hf = __uint_as_float(hb << 16);
        unsigned lb = bf16_rne_bits(w - hf);
        th[col * 128 + k] = (unsigned short)hb;
        tl[col * 128 + k] = (unsigned short)lb;
        return;
    }
    for (int i = threadIdx.x; i < NB; i += 256) { hD[i] = 0; hS[i] = 0; }
    __syncthreads();
    int c = blockIdx.x;
    int lo = c * CE;
    for (int i = lo + threadIdx.x; i < lo + CE; i += 256) {
        int d = dst[i];
        int s = src[i];
        unsigned rD = atomicAdd(&hD[d >> 7], 1u);
        unsigned rS = atomicAdd(&hS[s >> 7], 1u);
        ranks[i] = rD | (rS << 16);
    }
    __syncthreads();
    for (int i = threadIdx.x; i < NB; i += 256) {
        cntD[c * NB + i] = hD[i];
        cntS[c * NB + i] = hS[i];
    }
}

// ---- A2: exclusive column scan over chunks (in-place cnt -> colbase) + totals ----
__global__ __launch_bounds__(512) void colscan_kernel(
        unsigned* __restrict__ cntD, unsigned* __restrict__ cntS,
        unsigned* __restrict__ totD, unsigned* __restrict__ totS) {
    int bb = blockIdx.x;
    unsigned* cnt = (bb < NB) ? cntD : cntS;
    unsigned* tot = (bb < NB) ? totD : totS;
    int col = (bb < NB) ? bb : bb - NB;
    __shared__ unsigned buf[512];
    int t = threadIdx.x;
    unsigned v = (t < NC) ? cnt[t * NB + col] : 0;
    buf[t] = v;
    __syncthreads();
    for (int off = 1; off < 512; off <<= 1) {
        unsigned add = (t >= off) ? buf[t - off] : 0;
        __syncthreads();
        buf[t] += add;
        __syncthreads();
    }
    if (t < NC) cnt[t * NB + col] = buf[t] - v;   // exclusive
    if (t == NC - 1) tot[col] = buf[t];
}

// ---- A3: rank-addressed scatter into fixed bucket slabs (no atomics) ----
__global__ __launch_bounds__(256) void scatter_kernel(
        const int* __restrict__ src, const int* __restrict__ dst,
        const unsigned* __restrict__ ranks,
        const unsigned* __restrict__ colbaseD, const unsigned* __restrict__ colbaseS,
        unsigned* __restrict__ arenaD, unsigned char* __restrict__ arenaS) {
    __shared__ unsigned cbD[NB], cbS[NB];
    int c = blockIdx.x;
    for (int i = threadIdx.x; i < NB; i += 256) {
        cbD[i] = colbaseD[c * NB + i];
        cbS[i] = colbaseS[c * NB + i];
    }
    __syncthreads();
    int lo = c * CE;
    for (int i = lo + threadIdx.x; i < lo + CE; i += 256) {
        int d = dst[i];
        int s = src[i];
        unsigned rr = ranks[i];
        unsigned posD = (unsigned)(d >> 7) * SLAB + cbD[d >> 7] + (rr & 0xFFFFu);
        arenaD[posD] = (unsigned)s | ((unsigned)(d & 127) << 16);
        unsigned posS = (unsigned)(s >> 7) * SLAB + cbS[s >> 7] + (rr >> 16);
        arenaS[posS] = (unsigned char)(s & 127);
    }
}

// ---- B: per-bucket finalize. CSR rows sorted by src-half (lo seg | hi seg, each
// 8-padded with ZROW sentinels) -> agg streams lo-half first: 3.2MB L2 phase. ----
__global__ __launch_bounds__(256) void finalize_kernel(
        const unsigned* __restrict__ arenaD, const unsigned* __restrict__ totD,
        const unsigned char* __restrict__ arenaS, const unsigned* __restrict__ totS,
        unsigned short* __restrict__ csr, unsigned* __restrict__ row_start,
        unsigned* __restrict__ cnt2, unsigned* __restrict__ deg_out) {
    int b = blockIdx.x;
    __shared__ unsigned hlo[128], hhi[128], clo[128], chi[128], loc[128], sbuf[128];
    __shared__ unsigned short stag[CSLAB];
    int t = threadIdx.x;
    if (t < 128) { hlo[t] = 0; hhi[t] = 0; clo[t] = 0; chi[t] = 0; }
    for (int i = t; i < CSLAB; i += 256) stag[i] = (unsigned short)ZROW;
    __syncthreads();
    // src-bucket counts -> deg_out (uses clo as scratch, reset after)
    unsigned nbS = totS[b];
    const unsigned char* slabS = arenaS + (size_t)b * SLAB;
    for (unsigned i = t; i < nbS; i += 256) atomicAdd(&clo[slabS[i]], 1u);
    __syncthreads();
    if (t < 128) {
        int ss = b * 128 + t;
        if (ss < N_NODES) deg_out[ss] = clo[t];
        clo[t] = 0;
    }
    __syncthreads();
    // dst-bucket counts split by src-half
    unsigned nb = totD[b];
    const unsigned* slab = arenaD + (size_t)b * SLAB;
    for (unsigned i = t; i < nb; i += 256) {
        unsigned e = slab[i];
        if ((e & 0xFFFFu) < SRC_MID) atomicAdd(&hlo[e >> 16], 1u);
        else atomicAdd(&hhi[e >> 16], 1u);
    }
    __syncthreads();
    unsigned myv = 0;
    if (t < 128) {
        myv = ((hlo[t] + 7u) & ~7u) + ((hhi[t] + 7u) & ~7u);
        sbuf[t] = myv;
    }
    __syncthreads();
    for (int off = 1; off < 128; off <<= 1) {
        unsigned add = 0;
        if (t < 128 && t >= off) add = sbuf[t - off];
        __syncthreads();
        if (t < 128) sbuf[t] += add;
        __syncthreads();
    }
    if (t < 128) {
        loc[t] = sbuf[t] - myv;
        int dd = b * 128 + t;
        if (dd < N_NODES) {
            cnt2[dd] = hlo[t] | (hhi[t] << 16);
            row_start[dd] = (unsigned)b * CSLAB + loc[t];
        }
    }
    __syncthreads();
    for (unsigned i = t; i < nb; i += 256) {
        unsigned e = slab[i];
        unsigned dl = e >> 16;
        unsigned s = e & 0xFFFFu;
        unsigned pos;
        if (s < SRC_MID) pos = loc[dl] + atomicAdd(&clo[dl], 1u);
        else pos = loc[dl] + ((hlo[dl] + 7u) & ~7u) + atomicAdd(&chi[dl], 1u);
        stag[pos] = (unsigned short)s;
    }
    __syncthreads();
    unsigned tot_aligned = sbuf[127];
    unsigned short* g = csr + (size_t)b * CSLAB;
    for (unsigned i = t; i < tot_aligned; i += 256) g[i] = stag[i];
}

// ---- norms + graph ranges + prescale to bf16; node ZROW -> zero row ----
__global__ void norm_prescale_kernel(const unsigned* __restrict__ deg_out,
                                     const unsigned* __restrict__ cnt2,
                                     const float* __restrict__ X, unsigned* __restrict__ Xs,
                                     float* __restrict__ norm_in_a, float* __restrict__ norm_out_a,
                                     const int* __restrict__ gids,
                                     int* __restrict__ gstart, int* __restrict__ gend) {
    int gid = blockIdx.x * blockDim.x + threadIdx.x;
    if (gid >= (N_NODES + 1) * 16) return;
    int node = gid >> 4;
    int c = gid & 15;
    if (node >= N_NODES) {   // zero sentinel row (stays zero: gemm writes rows < N_NODES)
        uint4 z = {0u, 0u, 0u, 0u};
        *reinterpret_cast<uint4*>(Xs + (size_t)node * (FEATS / 2) + c * 4) = z;
        return;
    }
    unsigned d0 = deg_out[node];
    float no = d0 > 0 ? rsqrtf((float)d0) : 0.f;
    float4 a0 = *reinterpret_cast<const float4*>(X + (size_t)node * FEATS + c * 8);
    float4 a1 = *reinterpret_cast<const float4*>(X + (size_t)node * FEATS + c * 8 + 4);
    uint4 p;
    p.x = pack_bf16(a0.x * no, a0.y * no);
    p.y = pack_bf16(a0.z * no, a0.w * no);
    p.z = pack_bf16(a1.x * no, a1.y * no);
    p.w = pack_bf16(a1.z * no, a1.w * no);
    *reinterpret_cast<uint4*>(Xs + (size_t)node * (FEATS / 2) + c * 4) = p;
    if (c == 0) {
        norm_out_a[node] = no;
        unsigned c2 = cnt2[node];
        unsigned d1 = (c2 & 0xFFFFu) + (c2 >> 16);
        norm_in_a[node] = d1 > 0 ? rsqrtf((float)d1) : 0.f;
        int g = gids[node];
        if (node == 0 || gids[node - 1] != g) gstart[g] = node;
        if (node == N_NODES - 1 || gids[node + 1] != g) gend[g] = node + 1;
    }
}

// ---- pull aggregation: 16 lanes/node x uint2 (one 128B line per node-phase),
// column phase = blockIdx&1; rows sorted by src-half -> ~3.2MB live L2 set ----
__global__ __launch_bounds__(256) void agg_kernel(const unsigned* __restrict__ Xs,
        const unsigned short* __restrict__ csr, const unsigned* __restrict__ row_start,
        const unsigned* __restrict__ cnt2, unsigned* __restrict__ out) {
    int b = blockIdx.x;
    int h = b & 1;
    int node = (b >> 1) * 16 + (threadIdx.x >> 4);
    if (node >= N_NODES) return;
    int lane = threadIdx.x & 15;
    unsigned c2 = cnt2[node];
    unsigned ntot = (((c2 & 0xFFFFu) + 7u) & ~7u) + (((c2 >> 16) + 7u) & ~7u);
    const unsigned short* row = csr + row_start[node];
    const unsigned base = h * 32 + lane * 2;   // uint offset within 64-uint row
    float a0 = 0.f, a1 = 0.f, a2 = 0.f, a3 = 0.f;
    for (unsigned j = 0; j < ntot; j += 8) {
        uint4 iv = *reinterpret_cast<const uint4*>(row + j);
        unsigned s0 = iv.x & 0xFFFFu, s1 = iv.x >> 16;
        unsigned s2 = iv.y & 0xFFFFu, s3 = iv.y >> 16;
        unsigned s4 = iv.z & 0xFFFFu, s5 = iv.z >> 16;
        unsigned s6 = iv.w & 0xFFFFu, s7 = iv.w >> 16;
        uint2 g0 = *reinterpret_cast<const uint2*>(Xs + (size_t)s0 * 64 + base);
        uint2 g1 = *reinterpret_cast<const uint2*>(Xs + (size_t)s1 * 64 + base);
        uint2 g2 = *reinterpret_cast<const uint2*>(Xs + (size_t)s2 * 64 + base);
        uint2 g3 = *reinterpret_cast<const uint2*>(Xs + (size_t)s3 * 64 + base);
        uint2 g4 = *reinterpret_cast<const uint2*>(Xs + (size_t)s4 * 64 + base);
        uint2 g5 = *reinterpret_cast<const uint2*>(Xs + (size_t)s5 * 64 + base);
        uint2 g6 = *reinterpret_cast<const uint2*>(Xs + (size_t)s6 * 64 + base);
        uint2 g7 = *reinterpret_cast<const uint2*>(Xs + (size_t)s7 * 64 + base);
        a0 += ((bf16lo(g0.x) + bf16lo(g1.x)) + (bf16lo(g2.x) + bf16lo(g3.x)))
            + ((bf16lo(g4.x) + bf16lo(g5.x)) + (bf16lo(g6.x) + bf16lo(g7.x)));
        a1 += ((bf16hi(g0.x) + bf16hi(g1.x)) + (bf16hi(g2.x) + bf16hi(g3.x)))
            + ((bf16hi(g4.x) + bf16hi(g5.x)) + (bf16hi(g6.x) + bf16hi(g7.x)));
        a2 += ((bf16lo(g0.y) + bf16lo(g1.y)) + (bf16lo(g2.y) + bf16lo(g3.y)))
            + ((bf16lo(g4.y) + bf16lo(g5.y)) + (bf16lo(g6.y) + bf16lo(g7.y)));
        a3 += ((bf16hi(g0.y) + bf16hi(g1.y)) + (bf16hi(g2.y) + bf16hi(g3.y)))
            + ((bf16hi(g4.y) + bf16hi(g5.y)) + (bf16hi(g6.y) + bf16hi(g7.y)));
    }
    uint2 o;
    o.x = pack_bf16(a0, a1);
    o.y = pack_bf16(a2, a3);
    *reinterpret_cast<uint2*>(out + (size_t)node * 64 + base) = o;
}

// ---- MFMA gemm (16x16x32 bf16, split-W f32-accurate) ----
template <bool BF16_OUT>
__global__ __launch_bounds__(256) void gemm_kernel(
        const unsigned* __restrict__ A,
        const unsigned short* __restrict__ Wth, const unsigned short* __restrict__ Wtl,
        const float* __restrict__ bias, const float* __restrict__ norm_in,
        const float* __restrict__ post, float* __restrict__ out_f32,
        unsigned short* __restrict__ out_b16, int n_rows) {
    __shared__ unsigned sWh[128 * 68];
    __shared__ unsigned sWl[128 * 68];
    {
        const uint4* gh = reinterpret_cast<const uint4*>(Wth);
        const uint4* gl = reinterpret_cast<const uint4*>(Wtl);
        for (int i = threadIdx.x; i < 2048; i += 256) {
            int col = i >> 4, q = i & 15;
            *reinterpret_cast<uint4*>(sWh + col * 68 + q * 4) = gh[i];
            *reinterpret_cast<uint4*>(sWl + col * 68 + q * 4) = gl[i];
        }
    }
    __syncthreads();

    const int l = threadIdx.x & 63;
    const int w = threadIdx.x >> 6;
    const int rl = l & 15;
    const int kg = l >> 4;
    const int row0 = blockIdx.x * 64 + w * 16;

    int row_a = row0 + rl;
    if (row_a >= n_rows) row_a = n_rows - 1;
    const uint4* Arow = reinterpret_cast<const uint4*>(A + (size_t)row_a * 64);

    f32x4 acc[8];
#pragma unroll
    for (int ct = 0; ct < 8; ++ct) acc[ct] = (f32x4){0.f, 0.f, 0.f, 0.f};

#pragma unroll
    for (int s = 0; s < 4; ++s) {
        bf16x8 af = __builtin_bit_cast(bf16x8, Arow[4 * s + kg]);
#pragma unroll
        for (int ct = 0; ct < 8; ++ct) {
            int colb = ct * 16 + rl;
            bf16x8 bh = __builtin_bit_cast(bf16x8,
                *reinterpret_cast<const uint4*>(sWh + colb * 68 + 16 * s + 4 * kg));
            bf16x8 bl = __builtin_bit_cast(bf16x8,
                *reinterpret_cast<const uint4*>(sWl + colb * 68 + 16 * s + 4 * kg));
            acc[ct] = __builtin_amdgcn_mfma_f32_16x16x32_bf16(af, bl, acc[ct], 0, 0, 0);
            acc[ct] = __builtin_amdgcn_mfma_f32_16x16x32_bf16(af, bh, acc[ct], 0, 0, 0);
        }
    }

    const int rb = row0 + kg * 4;
    float ni[4], po[4];
#pragma unroll
    for (int j = 0; j < 4; ++j) {
        int r = rb + j;
        bool v = r < n_rows;
        ni[j] = v ? norm_in[r] : 0.f;
        po[j] = (BF16_OUT && v) ? post[r] : 1.f;
    }
#pragma unroll
    for (int ct = 0; ct < 8; ++ct) {
        int col = ct * 16 + rl;
        float bc = bias[col];
#pragma unroll
        for (int j = 0; j < 4; ++j) {
            int r = rb + j;
            if (r < n_rows) {
                float o = fmaxf(fmaf(acc[ct][j], ni[j], bc), 0.f);
                if (BF16_OUT)
                    out_b16[(size_t)r * 128 + col] = (unsigned short)bf16_rne_bits(o * po[j]);
                else
                    out_f32[(size_t)r * 128 + col] = o;
            }
        }
    }
}

// ---- fused mean-pool + classifier: one block per graph ----
__global__ __launch_bounds__(256) void pool_final_kernel(
        const float* __restrict__ H, const int* __restrict__ gstart,
        const int* __restrict__ gend, const float* __restrict__ Wf,
        const float* __restrict__ bf, float* __restrict__ out) {
    int g = blockIdx.x;
    int s = gstart[g];
    int e = gend[g];
    int f = threadIdx.x & 127;
    int h = threadIdx.x >> 7;
    float acc = 0.f;
    for (int r = s + h; r < e; r += 2) acc += H[(size_t)r * FEATS + f];
    __shared__ float tmp[256];
    __shared__ float pooled[FEATS];
    tmp[threadIdx.x] = acc;
    __syncthreads();
    if (threadIdx.x < FEATS) {
        float inv = 1.0f / fmaxf((float)(e - s), 1.0f);
        pooled[threadIdx.x] = (tmp[threadIdx.x] + tmp[threadIdx.x + 128]) * inv;
    }
    __syncthreads();
    if (threadIdx.x < N_CLASSES) {
        int c = threadIdx.x;
        float d = bf[c];
        for (int k = 0; k < FEATS; ++k) d = fmaf(pooled[k], Wf[k * N_CLASSES + c], d);
        out[g * N_CLASSES + c] = d;
    }
}

extern "C" void kernel_launch(void* const* d_in, const int* in_sizes, int n_in,
                              void* d_out, int out_size, void* d_ws, size_t ws_size,
                              hipStream_t stream) {
    const float* features = (const float*)d_in[0];
    const float* W1 = (const float*)d_in[1];
    const float* b1 = (const float*)d_in[2];
    const float* W2 = (const float*)d_in[3];
    const float* b2 = (const float*)d_in[4];
    const float* Wf = (const float*)d_in[5];
    const float* bf = (const float*)d_in[6];
    const int* src = (const int*)d_in[7];
    const int* dst = (const int*)d_in[8];
    const int* gids = (const int*)d_in[9];
    float* out = (float*)d_out;

    // bump allocator over d_ws, 256B-aligned sections
    char* wp = (char*)d_ws;
    auto alloc = [&wp](size_t bytes) {
        char* p = wp;
        wp += (bytes + 255) & ~(size_t)255;
        return p;
    };
    unsigned* buf0u = (unsigned*)alloc(((size_t)N_NODES + 1) * 64 * 4);  // agg bf16 out
    float* buf1 = (float*)alloc((size_t)N_NODES * FEATS * 4 + 256);      // H2 f32 / B16(+ZROW) alias
    unsigned* B16 = (unsigned*)buf1;
    unsigned short* B16s = (unsigned short*)buf1;
    float* norm_in_a = (float*)alloc(N_NODES * 4);
    float* norm_out_a = (float*)alloc(N_NODES * 4);
    unsigned* deg_out = (unsigned*)alloc(N_NODES * 4);
    unsigned* cnt2 = (unsigned*)alloc(N_NODES * 4);
    unsigned* row_start = (unsigned*)alloc(N_NODES * 4);
    int* gboth = (int*)alloc(2 * N_GRAPHS * 4);
    int* gstart = gboth;
    int* gend = gboth + N_GRAPHS;
    unsigned short* t1h = (unsigned short*)alloc(4 * 16384 * 2);
    unsigned short* t1l = t1h + 16384;
    unsigned short* t2h = t1l + 16384;
    unsigned short* t2l = t2h + 16384;
    unsigned* cntD = (unsigned*)alloc((size_t)NC * NB * 4);
    unsigned* cntS = (unsigned*)alloc((size_t)NC * NB * 4);
    unsigned* totD = (unsigned*)alloc(NB * 4);
    unsigned* totS = (unsigned*)alloc(NB * 4);
    unsigned* arenaD = (unsigned*)alloc((size_t)NB * SLAB * 4);
    unsigned* ranks = (unsigned*)alloc((size_t)N_EDGES * 4);   // packed rD|rS<<16
    unsigned short* csr = (unsigned short*)ranks;              // aliases ranks (dead after A3)
    unsigned char* arenaS = (unsigned char*)alloc((size_t)NB * SLAB);

    (void)hipMemsetAsync(gboth, 0, 2 * N_GRAPHS * sizeof(int), stream);

    // CSR build, zero global atomics (wsplit rides in countrank's tail blocks)
    countrank_kernel<<<NC + 128, 256, 0, stream>>>(src, dst, ranks, cntD, cntS,
                                                   W1, W2, t1h, t1l, t2h, t2l);
    colscan_kernel<<<2 * NB, 512, 0, stream>>>(cntD, cntS, totD, totS);
    scatter_kernel<<<NC, 256, 0, stream>>>(src, dst, ranks, cntD, cntS, arenaD, arenaS);
    finalize_kernel<<<NB, 256, 0, stream>>>(arenaD, totD, arenaS, totS,
                                            csr, row_start, cnt2, deg_out);

    norm_prescale_kernel<<<((N_NODES + 1) * 16 + 255) / 256, 256, 0, stream>>>(
        deg_out, cnt2, features, B16, norm_in_a, norm_out_a, gids, gstart, gend);

    const int agg_blocks = 2 * ((N_NODES + 15) / 16);   // x2: column-phase in blockIdx&1
    const int gemm_blocks = (N_NODES + 63) / 64;

    // layer 1: agg over bf16 Xs -> bf16 A; MFMA gemm folds norm_out, packs bf16 h1
    agg_kernel<<<agg_blocks, 256, 0, stream>>>(B16, csr, row_start, cnt2, buf0u);
    gemm_kernel<true><<<gemm_blocks, 256, 0, stream>>>(
        buf0u, t1h, t1l, b1, norm_in_a, norm_out_a, nullptr, B16s, N_NODES);

    // layer 2: agg over bf16 h1; MFMA gemm writes f32 H2
    agg_kernel<<<agg_blocks, 256, 0, stream>>>(B16, csr, row_start, cnt2, buf0u);
    gemm_kernel<false><<<gemm_blocks, 256, 0, stream>>>(
        buf0u, t2h, t2l, b2, norm_in_a, nullptr, buf1, nullptr, N_NODES);

    // fused pooling + classifier
    pool_final_kernel<<<N_GRAPHS, 256, 0, stream>>>(buf1, gstart, gend, Wf, bf, out);
}

// Round 13
// 212.418 us; speedup vs baseline: 1.0638x; 1.0638x over previous
//
#include <hip/hip_runtime.h>

#define N_NODES 50000
#define N_EDGES 1600000
#define FEATS 128
#define N_GRAPHS 512
#define N_CLASSES 16

#define NC 400      // edge chunks
#define CE 4000     // edges per chunk (NC*CE == N_EDGES)
#define NB 391      // buckets of 128 node-ids (391*128 = 50048)
#define SLAB 4608   // arena capacity per bucket (mean 4092, +8 sigma)
#define CSLAB 5632  // csr u16 slots per bucket (8-padded lo+hi segments, +8 sigma)
#define ZROW 50000  // sentinel node id -> zero row
#define SRC_MID 25000

typedef __attribute__((ext_vector_type(8))) short bf16x8;
typedef __attribute__((ext_vector_type(4))) float f32x4;

__device__ inline unsigned bf16_rne_bits(float x) {
    unsigned u = __float_as_uint(x);
    return (u + 0x7FFFu + ((u >> 16) & 1u)) >> 16;
}
__device__ inline unsigned pack_bf16(float a, float b) {
    return (bf16_rne_bits(b) << 16) | bf16_rne_bits(a);
}
__device__ inline float bf16lo(unsigned u) { return __uint_as_float(u << 16); }
__device__ inline float bf16hi(unsigned u) { return __uint_as_float(u & 0xFFFF0000u); }

// ---- A1: per-chunk bucket histograms + packed per-edge ranks; tail blocks do wsplit ----
__global__ __launch_bounds__(256) void countrank_kernel(
        const int* __restrict__ src, const int* __restrict__ dst,
        unsigned* __restrict__ ranks, unsigned* __restrict__ cntD, unsigned* __restrict__ cntS,
        const float* __restrict__ W1, const float* __restrict__ W2,
        unsigned short* __restrict__ t1h, unsigned short* __restrict__ t1l,
        unsigned short* __restrict__ t2h, unsigned short* __restrict__ t2l) {
    __shared__ unsigned hD[NB], hS[NB];
    if (blockIdx.x >= NC) {   // W -> transposed split-bf16 pair (128 blocks)
        int b = blockIdx.x - NC;
        const float* W = (b < 64) ? W1 : W2;
        unsigned short* th = (b < 64) ? t1h : t2h;
        unsigned short* tl = (b < 64) ? t1l : t2l;
        int idx = (b & 63) * 256 + threadIdx.x;
        int k = idx >> 7;
        int col = idx & 127;
        float w = W[idx];
        unsigned hb = bf16_rne_bits(w);
        float hf = __uint_as_float(hb << 16);
        unsigned lb = bf16_rne_bits(w - hf);
        th[col * 128 + k] = (unsigned short)hb;
        tl[col * 128 + k] = (unsigned short)lb;
        return;
    }
    for (int i = threadIdx.x; i < NB; i += 256) { hD[i] = 0; hS[i] = 0; }
    __syncthreads();
    int c = blockIdx.x;
    int lo = c * CE;
    for (int i = lo + threadIdx.x; i < lo + CE; i += 256) {
        int d = dst[i];
        int s = src[i];
        unsigned rD = atomicAdd(&hD[d >> 7], 1u);
        unsigned rS = atomicAdd(&hS[s >> 7], 1u);
        ranks[i] = rD | (rS << 16);
    }
    __syncthreads();
    for (int i = threadIdx.x; i < NB; i += 256) {
        cntD[c * NB + i] = hD[i];
        cntS[c * NB + i] = hS[i];
    }
}

// ---- A2: exclusive column scan over chunks (in-place cnt -> colbase) + totals ----
__global__ __launch_bounds__(512) void colscan_kernel(
        unsigned* __restrict__ cntD, unsigned* __restrict__ cntS,
        unsigned* __restrict__ totD, unsigned* __restrict__ totS) {
    int bb = blockIdx.x;
    unsigned* cnt = (bb < NB) ? cntD : cntS;
    unsigned* tot = (bb < NB) ? totD : totS;
    int col = (bb < NB) ? bb : bb - NB;
    __shared__ unsigned buf[512];
    int t = threadIdx.x;
    unsigned v = (t < NC) ? cnt[t * NB + col] : 0;
    buf[t] = v;
    __syncthreads();
    for (int off = 1; off < 512; off <<= 1) {
        unsigned add = (t >= off) ? buf[t - off] : 0;
        __syncthreads();
        buf[t] += add;
        __syncthreads();
    }
    if (t < NC) cnt[t * NB + col] = buf[t] - v;   // exclusive
    if (t == NC - 1) tot[col] = buf[t];
}

// ---- A3: rank-addressed scatter into fixed bucket slabs (no atomics) ----
__global__ __launch_bounds__(256) void scatter_kernel(
        const int* __restrict__ src, const int* __restrict__ dst,
        const unsigned* __restrict__ ranks,
        const unsigned* __restrict__ colbaseD, const unsigned* __restrict__ colbaseS,
        unsigned* __restrict__ arenaD, unsigned char* __restrict__ arenaS) {
    __shared__ unsigned cbD[NB], cbS[NB];
    int c = blockIdx.x;
    for (int i = threadIdx.x; i < NB; i += 256) {
        cbD[i] = colbaseD[c * NB + i];
        cbS[i] = colbaseS[c * NB + i];
    }
    __syncthreads();
    int lo = c * CE;
    for (int i = lo + threadIdx.x; i < lo + CE; i += 256) {
        int d = dst[i];
        int s = src[i];
        unsigned rr = ranks[i];
        unsigned posD = (unsigned)(d >> 7) * SLAB + cbD[d >> 7] + (rr & 0xFFFFu);
        arenaD[posD] = (unsigned)s | ((unsigned)(d & 127) << 16);
        unsigned posS = (unsigned)(s >> 7) * SLAB + cbS[s >> 7] + (rr >> 16);
        arenaS[posS] = (unsigned char)(s & 127);
    }
}

// ---- B: per-bucket finalize + FUSED prescale. Produces: cnt2, row_start,
// sentinel-padded src-sorted CSR, bf16 Xs rows for its 128 nodes, norms, graph ranges ----
__global__ __launch_bounds__(256) void finalize_kernel(
        const unsigned* __restrict__ arenaD, const unsigned* __restrict__ totD,
        const unsigned char* __restrict__ arenaS, const unsigned* __restrict__ totS,
        unsigned short* __restrict__ csr, unsigned* __restrict__ row_start,
        unsigned* __restrict__ cnt2,
        const float* __restrict__ X, unsigned* __restrict__ Xs,
        float* __restrict__ norm_in_a, float* __restrict__ norm_out_a,
        const int* __restrict__ gids, int* __restrict__ gstart, int* __restrict__ gend) {
    int b = blockIdx.x;
    __shared__ unsigned hlo[128], hhi[128], clo[128], chi[128], loc[128], sbuf[128], degs[128];
    __shared__ unsigned short stag[CSLAB];
    int t = threadIdx.x;
    if (t < 128) { hlo[t] = 0; hhi[t] = 0; clo[t] = 0; chi[t] = 0; }
    for (int i = t; i < CSLAB; i += 256) stag[i] = (unsigned short)ZROW;
    __syncthreads();
    // src-bucket counts -> degs (out-degree for this bucket's 128 nodes)
    unsigned nbS = totS[b];
    const unsigned char* slabS = arenaS + (size_t)b * SLAB;
    for (unsigned i = t; i < nbS; i += 256) atomicAdd(&clo[slabS[i]], 1u);
    __syncthreads();
    if (t < 128) { degs[t] = clo[t]; clo[t] = 0; }
    __syncthreads();
    // dst-bucket counts split by src-half
    unsigned nb = totD[b];
    const unsigned* slab = arenaD + (size_t)b * SLAB;
    for (unsigned i = t; i < nb; i += 256) {
        unsigned e = slab[i];
        if ((e & 0xFFFFu) < SRC_MID) atomicAdd(&hlo[e >> 16], 1u);
        else atomicAdd(&hhi[e >> 16], 1u);
    }
    __syncthreads();
    unsigned myv = 0;
    if (t < 128) {
        myv = ((hlo[t] + 7u) & ~7u) + ((hhi[t] + 7u) & ~7u);
        sbuf[t] = myv;
    }
    __syncthreads();
    for (int off = 1; off < 128; off <<= 1) {
        unsigned add = 0;
        if (t < 128 && t >= off) add = sbuf[t - off];
        __syncthreads();
        if (t < 128) sbuf[t] += add;
        __syncthreads();
    }
    if (t < 128) {
        loc[t] = sbuf[t] - myv;
        int dd = b * 128 + t;
        if (dd < N_NODES) {
            cnt2[dd] = hlo[t] | (hhi[t] << 16);
            row_start[dd] = (unsigned)b * CSLAB + loc[t];
        }
    }
    __syncthreads();
    for (unsigned i = t; i < nb; i += 256) {
        unsigned e = slab[i];
        unsigned dl = e >> 16;
        unsigned s = e & 0xFFFFu;
        unsigned pos;
        if (s < SRC_MID) pos = loc[dl] + atomicAdd(&clo[dl], 1u);
        else pos = loc[dl] + ((hlo[dl] + 7u) & ~7u) + atomicAdd(&chi[dl], 1u);
        stag[pos] = (unsigned short)s;
    }
    __syncthreads();
    unsigned tot_aligned = sbuf[127];
    unsigned short* g = csr + (size_t)b * CSLAB;
    for (unsigned i = t; i < tot_aligned; i += 256) g[i] = stag[i];
    // ---- fused prescale: Xs = bf16(norm_out * X) for nodes b*128..b*128+127 ----
    for (int task = t; task < 128 * 16; task += 256) {
        int nl = task >> 4;
        int c = task & 15;
        int node = b * 128 + nl;
        if (node < N_NODES) {
            unsigned d0 = degs[nl];
            float no = d0 > 0 ? rsqrtf((float)d0) : 0.f;
            float4 a0 = *reinterpret_cast<const float4*>(X + (size_t)node * FEATS + c * 8);
            float4 a1 = *reinterpret_cast<const float4*>(X + (size_t)node * FEATS + c * 8 + 4);
            uint4 p;
            p.x = pack_bf16(a0.x * no, a0.y * no);
            p.y = pack_bf16(a0.z * no, a0.w * no);
            p.z = pack_bf16(a1.x * no, a1.y * no);
            p.w = pack_bf16(a1.z * no, a1.w * no);
            *reinterpret_cast<uint4*>(Xs + (size_t)node * (FEATS / 2) + c * 4) = p;
        } else if (node == ZROW) {
            uint4 z = {0u, 0u, 0u, 0u};
            *reinterpret_cast<uint4*>(Xs + (size_t)node * (FEATS / 2) + c * 4) = z;
        }
    }
    if (t < 128) {
        int node = b * 128 + t;
        if (node < N_NODES) {
            unsigned d0 = degs[t];
            norm_out_a[node] = d0 > 0 ? rsqrtf((float)d0) : 0.f;
            unsigned d1 = hlo[t] + hhi[t];
            norm_in_a[node] = d1 > 0 ? rsqrtf((float)d1) : 0.f;
            int g2 = gids[node];
            if (node == 0 || gids[node - 1] != g2) gstart[g2] = node;
            if (node == N_NODES - 1 || gids[node + 1] != g2) gend[g2] = node + 1;
        }
    }
}

// ---- pull aggregation (R11 structure): 32 lanes/node x 4B = one 128B line per
// gather; column phase = blockIdx&1 (XCD-parity L2 slicing); sentinel-padded rows ----
__global__ __launch_bounds__(256) void agg_kernel(const unsigned* __restrict__ Xs,
        const unsigned short* __restrict__ csr, const unsigned* __restrict__ row_start,
        const unsigned* __restrict__ cnt2, unsigned* __restrict__ out) {
    int b = blockIdx.x;
    int h = b & 1;
    int node = (b >> 1) * 8 + (threadIdx.x >> 5);
    if (node >= N_NODES) return;
    int lane = threadIdx.x & 31;
    unsigned c2 = cnt2[node];
    unsigned ntot = (((c2 & 0xFFFFu) + 7u) & ~7u) + (((c2 >> 16) + 7u) & ~7u);
    const unsigned short* row = csr + row_start[node];
    const unsigned base = h * 32 + lane;   // uint offset within 64-uint row
    float alo = 0.f, ahi = 0.f;
#pragma unroll 2
    for (unsigned j = 0; j < ntot; j += 8) {
        uint4 iv = *reinterpret_cast<const uint4*>(row + j);
        unsigned s0 = iv.x & 0xFFFFu, s1 = iv.x >> 16;
        unsigned s2 = iv.y & 0xFFFFu, s3 = iv.y >> 16;
        unsigned s4 = iv.z & 0xFFFFu, s5 = iv.z >> 16;
        unsigned s6 = iv.w & 0xFFFFu, s7 = iv.w >> 16;
        unsigned g0 = Xs[(size_t)s0 * 64 + base];
        unsigned g1 = Xs[(size_t)s1 * 64 + base];
        unsigned g2 = Xs[(size_t)s2 * 64 + base];
        unsigned g3 = Xs[(size_t)s3 * 64 + base];
        unsigned g4 = Xs[(size_t)s4 * 64 + base];
        unsigned g5 = Xs[(size_t)s5 * 64 + base];
        unsigned g6 = Xs[(size_t)s6 * 64 + base];
        unsigned g7 = Xs[(size_t)s7 * 64 + base];
        alo += ((bf16lo(g0) + bf16lo(g1)) + (bf16lo(g2) + bf16lo(g3)))
             + ((bf16lo(g4) + bf16lo(g5)) + (bf16lo(g6) + bf16lo(g7)));
        ahi += ((bf16hi(g0) + bf16hi(g1)) + (bf16hi(g2) + bf16hi(g3)))
             + ((bf16hi(g4) + bf16hi(g5)) + (bf16hi(g6) + bf16hi(g7)));
    }
    out[(size_t)node * 64 + base] = pack_bf16(alo, ahi);
}

// ---- MFMA gemm (16x16x32 bf16, split-W f32-accurate) ----
template <bool BF16_OUT>
__global__ __launch_bounds__(256) void gemm_kernel(
        const unsigned* __restrict__ A,
        const unsigned short* __restrict__ Wth, const unsigned short* __restrict__ Wtl,
        const float* __restrict__ bias, const float* __restrict__ norm_in,
        const float* __restrict__ post, float* __restrict__ out_f32,
        unsigned short* __restrict__ out_b16, int n_rows) {
    __shared__ unsigned sWh[128 * 68];
    __shared__ unsigned sWl[128 * 68];
    {
        const uint4* gh = reinterpret_cast<const uint4*>(Wth);
        const uint4* gl = reinterpret_cast<const uint4*>(Wtl);
        for (int i = threadIdx.x; i < 2048; i += 256) {
            int col = i >> 4, q = i & 15;
            *reinterpret_cast<uint4*>(sWh + col * 68 + q * 4) = gh[i];
            *reinterpret_cast<uint4*>(sWl + col * 68 + q * 4) = gl[i];
        }
    }
    __syncthreads();

    const int l = threadIdx.x & 63;
    const int w = threadIdx.x >> 6;
    const int rl = l & 15;
    const int kg = l >> 4;
    const int row0 = blockIdx.x * 64 + w * 16;

    int row_a = row0 + rl;
    if (row_a >= n_rows) row_a = n_rows - 1;
    const uint4* Arow = reinterpret_cast<const uint4*>(A + (size_t)row_a * 64);

    f32x4 acc[8];
#pragma unroll
    for (int ct = 0; ct < 8; ++ct) acc[ct] = (f32x4){0.f, 0.f, 0.f, 0.f};

#pragma unroll
    for (int s = 0; s < 4; ++s) {
        bf16x8 af = __builtin_bit_cast(bf16x8, Arow[4 * s + kg]);
#pragma unroll
        for (int ct = 0; ct < 8; ++ct) {
            int colb = ct * 16 + rl;
            bf16x8 bh = __builtin_bit_cast(bf16x8,
                *reinterpret_cast<const uint4*>(sWh + colb * 68 + 16 * s + 4 * kg));
            bf16x8 bl = __builtin_bit_cast(bf16x8,
                *reinterpret_cast<const uint4*>(sWl + colb * 68 + 16 * s + 4 * kg));
            acc[ct] = __builtin_amdgcn_mfma_f32_16x16x32_bf16(af, bl, acc[ct], 0, 0, 0);
            acc[ct] = __builtin_amdgcn_mfma_f32_16x16x32_bf16(af, bh, acc[ct], 0, 0, 0);
        }
    }

    const int rb = row0 + kg * 4;
    float ni[4], po[4];
#pragma unroll
    for (int j = 0; j < 4; ++j) {
        int r = rb + j;
        bool v = r < n_rows;
        ni[j] = v ? norm_in[r] : 0.f;
        po[j] = (BF16_OUT && v) ? post[r] : 1.f;
    }
#pragma unroll
    for (int ct = 0; ct < 8; ++ct) {
        int col = ct * 16 + rl;
        float bc = bias[col];
#pragma unroll
        for (int j = 0; j < 4; ++j) {
            int r = rb + j;
            if (r < n_rows) {
                float o = fmaxf(fmaf(acc[ct][j], ni[j], bc), 0.f);
                if (BF16_OUT)
                    out_b16[(size_t)r * 128 + col] = (unsigned short)bf16_rne_bits(o * po[j]);
                else
                    out_f32[(size_t)r * 128 + col] = o;
            }
        }
    }
}

// ---- fused mean-pool + classifier: one block per graph ----
__global__ __launch_bounds__(256) void pool_final_kernel(
        const float* __restrict__ H, const int* __restrict__ gstart,
        const int* __restrict__ gend, const float* __restrict__ Wf,
        const float* __restrict__ bf, float* __restrict__ out) {
    int g = blockIdx.x;
    int s = gstart[g];
    int e = gend[g];
    int f = threadIdx.x & 127;
    int h = threadIdx.x >> 7;
    float acc = 0.f;
    for (int r = s + h; r < e; r += 2) acc += H[(size_t)r * FEATS + f];
    __shared__ float tmp[256];
    __shared__ float pooled[FEATS];
    tmp[threadIdx.x] = acc;
    __syncthreads();
    if (threadIdx.x < FEATS) {
        float inv = 1.0f / fmaxf((float)(e - s), 1.0f);
        pooled[threadIdx.x] = (tmp[threadIdx.x] + tmp[threadIdx.x + 128]) * inv;
    }
    __syncthreads();
    if (threadIdx.x < N_CLASSES) {
        int c = threadIdx.x;
        float d = bf[c];
        for (int k = 0; k < FEATS; ++k) d = fmaf(pooled[k], Wf[k * N_CLASSES + c], d);
        out[g * N_CLASSES + c] = d;
    }
}

extern "C" void kernel_launch(void* const* d_in, const int* in_sizes, int n_in,
                              void* d_out, int out_size, void* d_ws, size_t ws_size,
                              hipStream_t stream) {
    const float* features = (const float*)d_in[0];
    const float* W1 = (const float*)d_in[1];
    const float* b1 = (const float*)d_in[2];
    const float* W2 = (const float*)d_in[3];
    const float* b2 = (const float*)d_in[4];
    const float* Wf = (const float*)d_in[5];
    const float* bf = (const float*)d_in[6];
    const int* src = (const int*)d_in[7];
    const int* dst = (const int*)d_in[8];
    const int* gids = (const int*)d_in[9];
    float* out = (float*)d_out;

    // bump allocator over d_ws, 256B-aligned sections
    char* wp = (char*)d_ws;
    auto alloc = [&wp](size_t bytes) {
        char* p = wp;
        wp += (bytes + 255) & ~(size_t)255;
        return p;
    };
    unsigned* buf0u = (unsigned*)alloc(((size_t)N_NODES + 1) * 64 * 4);  // agg bf16 out
    float* buf1 = (float*)alloc((size_t)N_NODES * FEATS * 4 + 256);      // H2 f32 / B16(+ZROW) alias
    unsigned* B16 = (unsigned*)buf1;
    unsigned short* B16s = (unsigned short*)buf1;
    float* norm_in_a = (float*)alloc(N_NODES * 4);
    float* norm_out_a = (float*)alloc(N_NODES * 4);
    unsigned* cnt2 = (unsigned*)alloc(N_NODES * 4);
    unsigned* row_start = (unsigned*)alloc(N_NODES * 4);
    int* gboth = (int*)alloc(2 * N_GRAPHS * 4);
    int* gstart = gboth;
    int* gend = gboth + N_GRAPHS;
    unsigned short* t1h = (unsigned short*)alloc(4 * 16384 * 2);
    unsigned short* t1l = t1h + 16384;
    unsigned short* t2h = t1l + 16384;
    unsigned short* t2l = t2h + 16384;
    unsigned* cntD = (unsigned*)alloc((size_t)NC * NB * 4);
    unsigned* cntS = (unsigned*)alloc((size_t)NC * NB * 4);
    unsigned* totD = (unsigned*)alloc(NB * 4);
    unsigned* totS = (unsigned*)alloc(NB * 4);
    unsigned* arenaD = (unsigned*)alloc((size_t)NB * SLAB * 4);
    unsigned* ranks = (unsigned*)alloc((size_t)N_EDGES * 4);   // packed rD|rS<<16
    unsigned short* csr = (unsigned short*)ranks;              // aliases ranks (dead after A3)
    unsigned char* arenaS = (unsigned char*)alloc((size_t)NB * SLAB);

    (void)hipMemsetAsync(gboth, 0, 2 * N_GRAPHS * sizeof(int), stream);

    // CSR build, zero global atomics (wsplit rides in countrank's tail blocks)
    countrank_kernel<<<NC + 128, 256, 0, stream>>>(src, dst, ranks, cntD, cntS,
                                                   W1, W2, t1h, t1l, t2h, t2l);
    colscan_kernel<<<2 * NB, 512, 0, stream>>>(cntD, cntS, totD, totS);
    scatter_kernel<<<NC, 256, 0, stream>>>(src, dst, ranks, cntD, cntS, arenaD, arenaS);
    finalize_kernel<<<NB, 256, 0, stream>>>(arenaD, totD, arenaS, totS,
                                            csr, row_start, cnt2,
                                            features, B16, norm_in_a, norm_out_a,
                                            gids, gstart, gend);

    const int agg_blocks = 2 * ((N_NODES + 7) / 8);   // x2: column-phase in blockIdx&1
    const int gemm_blocks = (N_NODES + 63) / 64;

    // layer 1: agg over bf16 Xs -> bf16 A; MFMA gemm folds norm_out, packs bf16 h1
    agg_kernel<<<agg_blocks, 256, 0, stream>>>(B16, csr, row_start, cnt2, buf0u);
    gemm_kernel<true><<<gemm_blocks, 256, 0, stream>>>(
        buf0u, t1h, t1l, b1, norm_in_a, norm_out_a, nullptr, B16s, N_NODES);

    // layer 2: agg over bf16 h1; MFMA gemm writes f32 H2
    agg_kernel<<<agg_blocks, 256, 0, stream>>>(B16, csr, row_start, cnt2, buf0u);
    gemm_kernel<false><<<gemm_blocks, 256, 0, stream>>>(
        buf0u, t2h, t2l, b2, norm_in_a, nullptr, buf1, nullptr, N_NODES);

    // fused pooling + classifier
    pool_final_kernel<<<N_GRAPHS, 256, 0, stream>>>(buf1, gstart, gend, Wf, bf, out);
}

// Round 14
// 207.160 us; speedup vs baseline: 1.0908x; 1.0254x over previous
//
#include <hip/hip_runtime.h>

#define N_NODES 50000
#define N_EDGES 1600000
#define FEATS 128
#define N_GRAPHS 512
#define N_CLASSES 16

#define NC 400      // edge chunks
#define CE 4000     // edges per chunk (NC*CE == N_EDGES)
#define NB 391      // buckets of 128 node-ids (391*128 = 50048)
#define SLAB 4608   // arena capacity per bucket (mean 4092, +8 sigma)
#define CSLAB 5632  // csr u16 slots per bucket (8-padded lo+hi segments, +8 sigma)
#define ZROW 50000  // sentinel node id -> zero row
#define SRC_MID 25000

typedef __attribute__((ext_vector_type(8))) short bf16x8;
typedef __attribute__((ext_vector_type(4))) float f32x4;

__device__ inline unsigned bf16_rne_bits(float x) {
    unsigned u = __float_as_uint(x);
    return (u + 0x7FFFu + ((u >> 16) & 1u)) >> 16;
}
__device__ inline unsigned pack_bf16(float a, float b) {
    return (bf16_rne_bits(b) << 16) | bf16_rne_bits(a);
}
__device__ inline float bf16lo(unsigned u) { return __uint_as_float(u << 16); }
__device__ inline float bf16hi(unsigned u) { return __uint_as_float(u & 0xFFFF0000u); }

// ---- A1: per-chunk bucket histograms + packed per-edge ranks; tail blocks do
// wsplit; first tail block also zeroes gstart/gend (replaces hipMemsetAsync,
// which cost ~40us/replay as a fill kernel in the captured graph - R13 profile) ----
__global__ __launch_bounds__(256) void countrank_kernel(
        const int* __restrict__ src, const int* __restrict__ dst,
        unsigned* __restrict__ ranks, unsigned* __restrict__ cntD, unsigned* __restrict__ cntS,
        const float* __restrict__ W1, const float* __restrict__ W2,
        unsigned short* __restrict__ t1h, unsigned short* __restrict__ t1l,
        unsigned short* __restrict__ t2h, unsigned short* __restrict__ t2l,
        int* __restrict__ gboth) {
    __shared__ unsigned hD[NB], hS[NB];
    if (blockIdx.x >= NC) {   // W -> transposed split-bf16 pair (128 blocks)
        int b = blockIdx.x - NC;
        if (b == 0) {
#pragma unroll
            for (int i = 0; i < 4; ++i) gboth[threadIdx.x + 256 * i] = 0;
        }
        const float* W = (b < 64) ? W1 : W2;
        unsigned short* th = (b < 64) ? t1h : t2h;
        unsigned short* tl = (b < 64) ? t1l : t2l;
        int idx = (b & 63) * 256 + threadIdx.x;
        int k = idx >> 7;
        int col = idx & 127;
        float w = W[idx];
        unsigned hb = bf16_rne_bits(w);
        float hf = __uint_as_float(hb << 16);
        unsigned lb = bf16_rne_bits(w - hf);
        th[col * 128 + k] = (unsigned short)hb;
        tl[col * 128 + k] = (unsigned short)lb;
        return;
    }
    for (int i = threadIdx.x; i < NB; i += 256) { hD[i] = 0; hS[i] = 0; }
    __syncthreads();
    int c = blockIdx.x;
    int lo = c * CE;
    for (int i = lo + threadIdx.x; i < lo + CE; i += 256) {
        int d = dst[i];
        int s = src[i];
        unsigned rD = atomicAdd(&hD[d >> 7], 1u);
        unsigned rS = atomicAdd(&hS[s >> 7], 1u);
        ranks[i] = rD | (rS << 16);
    }
    __syncthreads();
    for (int i = threadIdx.x; i < NB; i += 256) {
        cntD[c * NB + i] = hD[i];
        cntS[c * NB + i] = hS[i];
    }
}

// ---- A2: exclusive column scan over chunks (in-place cnt -> colbase) + totals ----
__global__ __launch_bounds__(512) void colscan_kernel(
        unsigned* __restrict__ cntD, unsigned* __restrict__ cntS,
        unsigned* __restrict__ totD, unsigned* __restrict__ totS) {
    int bb = blockIdx.x;
    unsigned* cnt = (bb < NB) ? cntD : cntS;
    unsigned* tot = (bb < NB) ? totD : totS;
    int col = (bb < NB) ? bb : bb - NB;
    __shared__ unsigned buf[512];
    int t = threadIdx.x;
    unsigned v = (t < NC) ? cnt[t * NB + col] : 0;
    buf[t] = v;
    __syncthreads();
    for (int off = 1; off < 512; off <<= 1) {
        unsigned add = (t >= off) ? buf[t - off] : 0;
        __syncthreads();
        buf[t] += add;
        __syncthreads();
    }
    if (t < NC) cnt[t * NB + col] = buf[t] - v;   // exclusive
    if (t == NC - 1) tot[col] = buf[t];
}

// ---- A3: rank-addressed scatter into fixed bucket slabs (no atomics) ----
__global__ __launch_bounds__(256) void scatter_kernel(
        const int* __restrict__ src, const int* __restrict__ dst,
        const unsigned* __restrict__ ranks,
        const unsigned* __restrict__ colbaseD, const unsigned* __restrict__ colbaseS,
        unsigned* __restrict__ arenaD, unsigned char* __restrict__ arenaS) {
    __shared__ unsigned cbD[NB], cbS[NB];
    int c = blockIdx.x;
    for (int i = threadIdx.x; i < NB; i += 256) {
        cbD[i] = colbaseD[c * NB + i];
        cbS[i] = colbaseS[c * NB + i];
    }
    __syncthreads();
    int lo = c * CE;
    for (int i = lo + threadIdx.x; i < lo + CE; i += 256) {
        int d = dst[i];
        int s = src[i];
        unsigned rr = ranks[i];
        unsigned posD = (unsigned)(d >> 7) * SLAB + cbD[d >> 7] + (rr & 0xFFFFu);
        arenaD[posD] = (unsigned)s | ((unsigned)(d & 127) << 16);
        unsigned posS = (unsigned)(s >> 7) * SLAB + cbS[s >> 7] + (rr >> 16);
        arenaS[posS] = (unsigned char)(s & 127);
    }
}

// ---- B: per-bucket finalize + FUSED prescale. Produces: cnt2, row_start,
// sentinel-padded src-sorted CSR, bf16 Xs rows for its 128 nodes, norms, graph ranges ----
__global__ __launch_bounds__(256) void finalize_kernel(
        const unsigned* __restrict__ arenaD, const unsigned* __restrict__ totD,
        const unsigned char* __restrict__ arenaS, const unsigned* __restrict__ totS,
        unsigned short* __restrict__ csr, unsigned* __restrict__ row_start,
        unsigned* __restrict__ cnt2,
        const float* __restrict__ X, unsigned* __restrict__ Xs,
        float* __restrict__ norm_in_a, float* __restrict__ norm_out_a,
        const int* __restrict__ gids, int* __restrict__ gstart, int* __restrict__ gend) {
    int b = blockIdx.x;
    __shared__ unsigned hlo[128], hhi[128], clo[128], chi[128], loc[128], sbuf[128], degs[128];
    __shared__ unsigned short stag[CSLAB];
    int t = threadIdx.x;
    if (t < 128) { hlo[t] = 0; hhi[t] = 0; clo[t] = 0; chi[t] = 0; }
    for (int i = t; i < CSLAB; i += 256) stag[i] = (unsigned short)ZROW;
    __syncthreads();
    // src-bucket counts -> degs (out-degree for this bucket's 128 nodes)
    unsigned nbS = totS[b];
    const unsigned char* slabS = arenaS + (size_t)b * SLAB;
    for (unsigned i = t; i < nbS; i += 256) atomicAdd(&clo[slabS[i]], 1u);
    __syncthreads();
    if (t < 128) { degs[t] = clo[t]; clo[t] = 0; }
    __syncthreads();
    // dst-bucket counts split by src-half
    unsigned nb = totD[b];
    const unsigned* slab = arenaD + (size_t)b * SLAB;
    for (unsigned i = t; i < nb; i += 256) {
        unsigned e = slab[i];
        if ((e & 0xFFFFu) < SRC_MID) atomicAdd(&hlo[e >> 16], 1u);
        else atomicAdd(&hhi[e >> 16], 1u);
    }
    __syncthreads();
    unsigned myv = 0;
    if (t < 128) {
        myv = ((hlo[t] + 7u) & ~7u) + ((hhi[t] + 7u) & ~7u);
        sbuf[t] = myv;
    }
    __syncthreads();
    for (int off = 1; off < 128; off <<= 1) {
        unsigned add = 0;
        if (t < 128 && t >= off) add = sbuf[t - off];
        __syncthreads();
        if (t < 128) sbuf[t] += add;
        __syncthreads();
    }
    if (t < 128) {
        loc[t] = sbuf[t] - myv;
        int dd = b * 128 + t;
        if (dd < N_NODES) {
            cnt2[dd] = hlo[t] | (hhi[t] << 16);
            row_start[dd] = (unsigned)b * CSLAB + loc[t];
        }
    }
    __syncthreads();
    for (unsigned i = t; i < nb; i += 256) {
        unsigned e = slab[i];
        unsigned dl = e >> 16;
        unsigned s = e & 0xFFFFu;
        unsigned pos;
        if (s < SRC_MID) pos = loc[dl] + atomicAdd(&clo[dl], 1u);
        else pos = loc[dl] + ((hlo[dl] + 7u) & ~7u) + atomicAdd(&chi[dl], 1u);
        stag[pos] = (unsigned short)s;
    }
    __syncthreads();
    unsigned tot_aligned = sbuf[127];
    unsigned short* g = csr + (size_t)b * CSLAB;
    for (unsigned i = t; i < tot_aligned; i += 256) g[i] = stag[i];
    // ---- fused prescale: Xs = bf16(norm_out * X) for nodes b*128..b*128+127 ----
    for (int task = t; task < 128 * 16; task += 256) {
        int nl = task >> 4;
        int c = task & 15;
        int node = b * 128 + nl;
        if (node < N_NODES) {
            unsigned d0 = degs[nl];
            float no = d0 > 0 ? rsqrtf((float)d0) : 0.f;
            float4 a0 = *reinterpret_cast<const float4*>(X + (size_t)node * FEATS + c * 8);
            float4 a1 = *reinterpret_cast<const float4*>(X + (size_t)node * FEATS + c * 8 + 4);
            uint4 p;
            p.x = pack_bf16(a0.x * no, a0.y * no);
            p.y = pack_bf16(a0.z * no, a0.w * no);
            p.z = pack_bf16(a1.x * no, a1.y * no);
            p.w = pack_bf16(a1.z * no, a1.w * no);
            *reinterpret_cast<uint4*>(Xs + (size_t)node * (FEATS / 2) + c * 4) = p;
        } else if (node == ZROW) {
            uint4 z = {0u, 0u, 0u, 0u};
            *reinterpret_cast<uint4*>(Xs + (size_t)node * (FEATS / 2) + c * 4) = z;
        }
    }
    if (t < 128) {
        int node = b * 128 + t;
        if (node < N_NODES) {
            unsigned d0 = degs[t];
            norm_out_a[node] = d0 > 0 ? rsqrtf((float)d0) : 0.f;
            unsigned d1 = hlo[t] + hhi[t];
            norm_in_a[node] = d1 > 0 ? rsqrtf((float)d1) : 0.f;
            int g2 = gids[node];
            if (node == 0 || gids[node - 1] != g2) gstart[g2] = node;
            if (node == N_NODES - 1 || gids[node + 1] != g2) gend[g2] = node + 1;
        }
    }
}

// ---- pull aggregation: 32 lanes/node x 4B = one 128B line per gather;
// column phase = blockIdx&1 (XCD-parity L2 slicing); sentinel-padded rows ----
__global__ __launch_bounds__(256) void agg_kernel(const unsigned* __restrict__ Xs,
        const unsigned short* __restrict__ csr, const unsigned* __restrict__ row_start,
        const unsigned* __restrict__ cnt2, unsigned* __restrict__ out) {
    int b = blockIdx.x;
    int h = b & 1;
    int node = (b >> 1) * 8 + (threadIdx.x >> 5);
    if (node >= N_NODES) return;
    int lane = threadIdx.x & 31;
    unsigned c2 = cnt2[node];
    unsigned ntot = (((c2 & 0xFFFFu) + 7u) & ~7u) + (((c2 >> 16) + 7u) & ~7u);
    const unsigned short* row = csr + row_start[node];
    const unsigned base = h * 32 + lane;   // uint offset within 64-uint row
    float alo = 0.f, ahi = 0.f;
#pragma unroll 2
    for (unsigned j = 0; j < ntot; j += 8) {
        uint4 iv = *reinterpret_cast<const uint4*>(row + j);
        unsigned s0 = iv.x & 0xFFFFu, s1 = iv.x >> 16;
        unsigned s2 = iv.y & 0xFFFFu, s3 = iv.y >> 16;
        unsigned s4 = iv.z & 0xFFFFu, s5 = iv.z >> 16;
        unsigned s6 = iv.w & 0xFFFFu, s7 = iv.w >> 16;
        unsigned g0 = Xs[(size_t)s0 * 64 + base];
        unsigned g1 = Xs[(size_t)s1 * 64 + base];
        unsigned g2 = Xs[(size_t)s2 * 64 + base];
        unsigned g3 = Xs[(size_t)s3 * 64 + base];
        unsigned g4 = Xs[(size_t)s4 * 64 + base];
        unsigned g5 = Xs[(size_t)s5 * 64 + base];
        unsigned g6 = Xs[(size_t)s6 * 64 + base];
        unsigned g7 = Xs[(size_t)s7 * 64 + base];
        alo += ((bf16lo(g0) + bf16lo(g1)) + (bf16lo(g2) + bf16lo(g3)))
             + ((bf16lo(g4) + bf16lo(g5)) + (bf16lo(g6) + bf16lo(g7)));
        ahi += ((bf16hi(g0) + bf16hi(g1)) + (bf16hi(g2) + bf16hi(g3)))
             + ((bf16hi(g4) + bf16hi(g5)) + (bf16hi(g6) + bf16hi(g7)));
    }
    out[(size_t)node * 64 + base] = pack_bf16(alo, ahi);
}

// ---- MFMA gemm (16x16x32 bf16, split-W f32-accurate) ----
template <bool BF16_OUT>
__global__ __launch_bounds__(256) void gemm_kernel(
        const unsigned* __restrict__ A,
        const unsigned short* __restrict__ Wth, const unsigned short* __restrict__ Wtl,
        const float* __restrict__ bias, const float* __restrict__ norm_in,
        const float* __restrict__ post, float* __restrict__ out_f32,
        unsigned short* __restrict__ out_b16, int n_rows) {
    __shared__ unsigned sWh[128 * 68];
    __shared__ unsigned sWl[128 * 68];
    {
        const uint4* gh = reinterpret_cast<const uint4*>(Wth);
        const uint4* gl = reinterpret_cast<const uint4*>(Wtl);
        for (int i = threadIdx.x; i < 2048; i += 256) {
            int col = i >> 4, q = i & 15;
            *reinterpret_cast<uint4*>(sWh + col * 68 + q * 4) = gh[i];
            *reinterpret_cast<uint4*>(sWl + col * 68 + q * 4) = gl[i];
        }
    }
    __syncthreads();

    const int l = threadIdx.x & 63;
    const int w = threadIdx.x >> 6;
    const int rl = l & 15;
    const int kg = l >> 4;
    const int row0 = blockIdx.x * 64 + w * 16;

    int row_a = row0 + rl;
    if (row_a >= n_rows) row_a = n_rows - 1;
    const uint4* Arow = reinterpret_cast<const uint4*>(A + (size_t)row_a * 64);

    f32x4 acc[8];
#pragma unroll
    for (int ct = 0; ct < 8; ++ct) acc[ct] = (f32x4){0.f, 0.f, 0.f, 0.f};

#pragma unroll
    for (int s = 0; s < 4; ++s) {
        bf16x8 af = __builtin_bit_cast(bf16x8, Arow[4 * s + kg]);
#pragma unroll
        for (int ct = 0; ct < 8; ++ct) {
            int colb = ct * 16 + rl;
            bf16x8 bh = __builtin_bit_cast(bf16x8,
                *reinterpret_cast<const uint4*>(sWh + colb * 68 + 16 * s + 4 * kg));
            bf16x8 bl = __builtin_bit_cast(bf16x8,
                *reinterpret_cast<const uint4*>(sWl + colb * 68 + 16 * s + 4 * kg));
            acc[ct] = __builtin_amdgcn_mfma_f32_16x16x32_bf16(af, bl, acc[ct], 0, 0, 0);
            acc[ct] = __builtin_amdgcn_mfma_f32_16x16x32_bf16(af, bh, acc[ct], 0, 0, 0);
        }
    }

    const int rb = row0 + kg * 4;
    float ni[4], po[4];
#pragma unroll
    for (int j = 0; j < 4; ++j) {
        int r = rb + j;
        bool v = r < n_rows;
        ni[j] = v ? norm_in[r] : 0.f;
        po[j] = (BF16_OUT && v) ? post[r] : 1.f;
    }
#pragma unroll
    for (int ct = 0; ct < 8; ++ct) {
        int col = ct * 16 + rl;
        float bc = bias[col];
#pragma unroll
        for (int j = 0; j < 4; ++j) {
            int r = rb + j;
            if (r < n_rows) {
                float o = fmaxf(fmaf(acc[ct][j], ni[j], bc), 0.f);
                if (BF16_OUT)
                    out_b16[(size_t)r * 128 + col] = (unsigned short)bf16_rne_bits(o * po[j]);
                else
                    out_f32[(size_t)r * 128 + col] = o;
            }
        }
    }
}

// ---- fused mean-pool + classifier: one block per graph ----
__global__ __launch_bounds__(256) void pool_final_kernel(
        const float* __restrict__ H, const int* __restrict__ gstart,
        const int* __restrict__ gend, const float* __restrict__ Wf,
        const float* __restrict__ bf, float* __restrict__ out) {
    int g = blockIdx.x;
    int s = gstart[g];
    int e = gend[g];
    int f = threadIdx.x & 127;
    int h = threadIdx.x >> 7;
    float acc = 0.f;
    for (int r = s + h; r < e; r += 2) acc += H[(size_t)r * FEATS + f];
    __shared__ float tmp[256];
    __shared__ float pooled[FEATS];
    tmp[threadIdx.x] = acc;
    __syncthreads();
    if (threadIdx.x < FEATS) {
        float inv = 1.0f / fmaxf((float)(e - s), 1.0f);
        pooled[threadIdx.x] = (tmp[threadIdx.x] + tmp[threadIdx.x + 128]) * inv;
    }
    __syncthreads();
    if (threadIdx.x < N_CLASSES) {
        int c = threadIdx.x;
        float d = bf[c];
        for (int k = 0; k < FEATS; ++k) d = fmaf(pooled[k], Wf[k * N_CLASSES + c], d);
        out[g * N_CLASSES + c] = d;
    }
}

extern "C" void kernel_launch(void* const* d_in, const int* in_sizes, int n_in,
                              void* d_out, int out_size, void* d_ws, size_t ws_size,
                              hipStream_t stream) {
    const float* features = (const float*)d_in[0];
    const float* W1 = (const float*)d_in[1];
    const float* b1 = (const float*)d_in[2];
    const float* W2 = (const float*)d_in[3];
    const float* b2 = (const float*)d_in[4];
    const float* Wf = (const float*)d_in[5];
    const float* bf = (const float*)d_in[6];
    const int* src = (const int*)d_in[7];
    const int* dst = (const int*)d_in[8];
    const int* gids = (const int*)d_in[9];
    float* out = (float*)d_out;

    // bump allocator over d_ws, 256B-aligned sections
    char* wp = (char*)d_ws;
    auto alloc = [&wp](size_t bytes) {
        char* p = wp;
        wp += (bytes + 255) & ~(size_t)255;
        return p;
    };
    unsigned* buf0u = (unsigned*)alloc(((size_t)N_NODES + 1) * 64 * 4);  // agg bf16 out
    float* buf1 = (float*)alloc((size_t)N_NODES * FEATS * 4 + 256);      // H2 f32 / B16(+ZROW) alias
    unsigned* B16 = (unsigned*)buf1;
    unsigned short* B16s = (unsigned short*)buf1;
    float* norm_in_a = (float*)alloc(N_NODES * 4);
    float* norm_out_a = (float*)alloc(N_NODES * 4);
    unsigned* cnt2 = (unsigned*)alloc(N_NODES * 4);
    unsigned* row_start = (unsigned*)alloc(N_NODES * 4);
    int* gboth = (int*)alloc(2 * N_GRAPHS * 4);
    int* gstart = gboth;
    int* gend = gboth + N_GRAPHS;
    unsigned short* t1h = (unsigned short*)alloc(4 * 16384 * 2);
    unsigned short* t1l = t1h + 16384;
    unsigned short* t2h = t1l + 16384;
    unsigned short* t2l = t2h + 16384;
    unsigned* cntD = (unsigned*)alloc((size_t)NC * NB * 4);
    unsigned* cntS = (unsigned*)alloc((size_t)NC * NB * 4);
    unsigned* totD = (unsigned*)alloc(NB * 4);
    unsigned* totS = (unsigned*)alloc(NB * 4);
    unsigned* arenaD = (unsigned*)alloc((size_t)NB * SLAB * 4);
    unsigned* ranks = (unsigned*)alloc((size_t)N_EDGES * 4);   // packed rD|rS<<16
    unsigned short* csr = (unsigned short*)ranks;              // aliases ranks (dead after A3)
    unsigned char* arenaS = (unsigned char*)alloc((size_t)NB * SLAB);

    // CSR build, zero global atomics; no memsets in the graph (countrank zeroes gboth)
    countrank_kernel<<<NC + 128, 256, 0, stream>>>(src, dst, ranks, cntD, cntS,
                                                   W1, W2, t1h, t1l, t2h, t2l, gboth);
    colscan_kernel<<<2 * NB, 512, 0, stream>>>(cntD, cntS, totD, totS);
    scatter_kernel<<<NC, 256, 0, stream>>>(src, dst, ranks, cntD, cntS, arenaD, arenaS);
    finalize_kernel<<<NB, 256, 0, stream>>>(arenaD, totD, arenaS, totS,
                                            csr, row_start, cnt2,
                                            features, B16, norm_in_a, norm_out_a,
                                            gids, gstart, gend);

    const int agg_blocks = 2 * ((N_NODES + 7) / 8);   // x2: column-phase in blockIdx&1
    const int gemm_blocks = (N_NODES + 63) / 64;

    // layer 1: agg over bf16 Xs -> bf16 A; MFMA gemm folds norm_out, packs bf16 h1
    agg_kernel<<<agg_blocks, 256, 0, stream>>>(B16, csr, row_start, cnt2, buf0u);
    gemm_kernel<true><<<gemm_blocks, 256, 0, stream>>>(
        buf0u, t1h, t1l, b1, norm_in_a, norm_out_a, nullptr, B16s, N_NODES);

    // layer 2: agg over bf16 h1; MFMA gemm writes f32 H2
    agg_kernel<<<agg_blocks, 256, 0, stream>>>(B16, csr, row_start, cnt2, buf0u);
    gemm_kernel<false><<<gemm_blocks, 256, 0, stream>>>(
        buf0u, t2h, t2l, b2, norm_in_a, nullptr, buf1, nullptr, N_NODES);

    // fused pooling + classifier
    pool_final_kernel<<<N_GRAPHS, 256, 0, stream>>>(buf1, gstart, gend, Wf, bf, out);
}